// Round 3
// baseline (182.463 us; speedup 1.0000x reference)
//
#include <hip/hip_runtime.h>
#include <hip/hip_bf16.h>
#include <hip/hip_fp16.h>
#include <math.h>

// Decoder: out[e] = sigmoid(relu( W2 . relu( W1 * [x[src]; x[dst]] + b1 ) + b2 ))
// R3 factorization: W1*[xs;xd] = W1_left*xs + W1_right*xd
//   Phase A (per node, dense GEMM): Y[n][0:128]   = W1_left*x[n] + b1
//                                   Y[n][128:256] = W1_right*x[n]      (fp16)
//   Phase B (per edge, streaming):  out = sigmoid(relu(W2 . relu(Yl[src]+Yr[dst]) + b2))
// 6.3x fewer FLOPs than edge-wise GEMM; edge phase is barrier-free pure gather
// served by L3 (Y = 51.2 MB, L3-resident).

typedef short    s16x4 __attribute__((ext_vector_type(4)));
typedef short    s16x8 __attribute__((ext_vector_type(8)));
typedef float    f32x4 __attribute__((ext_vector_type(4)));
typedef _Float16 h16x8 __attribute__((ext_vector_type(8)));

#define D    128
#define BM   128
#define BK   64
#define LDT  72    // BK + 8 pad

static __device__ inline short f2bf(float f) {
    unsigned u = __builtin_bit_cast(unsigned, f);
    unsigned r = (u + 0x7FFFu + ((u >> 16) & 1u)) >> 16;
    return (short)r;
}

// ---------------- Phase A: Y[n][half*128+o] = W1[o][half*128+k] . x[n][k] (+b1 if half==0)
__global__ __launch_bounds__(256) void precompute_kernel(
    const float* __restrict__ x,    // [N,128]
    const float* __restrict__ W1,   // [128,256] row-major
    const float* __restrict__ b1,   // [128]
    _Float16*    __restrict__ Y,    // [N,256]
    int N)
{
    __shared__ short At[BM * LDT];
    __shared__ short Bt[D * LDT];

    const int tid  = threadIdx.x;
    const int m0   = blockIdx.x * BM;
    const int half = blockIdx.y;           // 0 = left, 1 = right

    const int wid  = tid >> 6;
    const int lane = tid & 63;
    const int wm = wid >> 1, wn = wid & 1;
    const int quad = lane >> 4, l15 = lane & 15;
    const int srow = tid >> 4;
    const int scol = (tid & 15) * 4;

    f32x4 acc[4][4] = {};

    for (int t = 0; t < 2; ++t) {
        const int k0 = t * BK;
        // stage A: x rows (streamed, fp32 -> bf16)
        #pragma unroll
        for (int p = 0; p < 8; ++p) {
            int row = srow + p * 16;
            int m = m0 + row; if (m >= N) m = N - 1;
            float4 v = *(const float4*)&x[(size_t)m * D + k0 + scol];
            s16x4 bv = { f2bf(v.x), f2bf(v.y), f2bf(v.z), f2bf(v.w) };
            *(s16x4*)&At[row * LDT + scol] = bv;
        }
        // stage B: W1 rows (B^T layout: n-major, k contiguous)
        #pragma unroll
        for (int p = 0; p < 8; ++p) {
            int o = srow + p * 16;
            float4 v = *(const float4*)&W1[o * 256 + half * D + k0 + scol];
            s16x4 bv = { f2bf(v.x), f2bf(v.y), f2bf(v.z), f2bf(v.w) };
            *(s16x4*)&Bt[o * LDT + scol] = bv;
        }
        __syncthreads();

        #pragma unroll
        for (int c = 0; c < 2; ++c) {
            const int kc = c * 32;
            s16x8 af[4], bfr[4];
            #pragma unroll
            for (int i = 0; i < 4; ++i)
                af[i] = *(const s16x8*)&At[(wm*64 + i*16 + l15) * LDT + kc + quad*8];
            #pragma unroll
            for (int j = 0; j < 4; ++j)
                bfr[j] = *(const s16x8*)&Bt[(wn*64 + j*16 + l15) * LDT + kc + quad*8];
            #pragma unroll
            for (int i = 0; i < 4; ++i)
                #pragma unroll
                for (int j = 0; j < 4; ++j)
                    acc[i][j] = __builtin_amdgcn_mfma_f32_16x16x32_bf16(
                        af[i], bfr[j], acc[i][j], 0, 0, 0);
        }
        __syncthreads();
    }

    // epilogue: fp16 store, fold b1 into left half
    // C/D layout: col = lane&15, row = quad*4 + reg
    #pragma unroll
    for (int j = 0; j < 4; ++j) {
        int col = wn*64 + j*16 + l15;
        float bb = (half == 0) ? b1[col] : 0.f;
        #pragma unroll
        for (int i = 0; i < 4; ++i) {
            int mrow = m0 + wm*64 + i*16 + quad*4;
            #pragma unroll
            for (int r = 0; r < 4; ++r) {
                int m = mrow + r;
                if (m < N)
                    Y[(size_t)m * 256 + half * D + col] = (_Float16)(acc[i][j][r] + bb);
            }
        }
    }
}

// ---------------- Phase B: per-edge streaming gather + dot(128) + sigmoid
__global__ __launch_bounds__(256) void edge_kernel(
    const _Float16* __restrict__ Y,   // [N,256]
    const int*      __restrict__ ei,  // [2,E]
    const float*    __restrict__ W2,  // [128]
    const float*    __restrict__ b2,  // [1]
    float*          __restrict__ out, // [E]
    int E)
{
    const int tid = threadIdx.x;
    const int sub = tid & 7;                    // 8 lanes per edge
    const int e   = blockIdx.x * 32 + (tid >> 3);

    float w2v[16];
    *(float4*)&w2v[0]  = *(const float4*)&W2[sub*16 + 0];
    *(float4*)&w2v[4]  = *(const float4*)&W2[sub*16 + 4];
    *(float4*)&w2v[8]  = *(const float4*)&W2[sub*16 + 8];
    *(float4*)&w2v[12] = *(const float4*)&W2[sub*16 + 12];

    if (e < E) {
        int src = ei[e];
        int dst = ei[E + e];
        const _Float16* pl = Y + (size_t)src * 256 + sub * 16;
        const _Float16* pr = Y + (size_t)dst * 256 + 128 + sub * 16;
        h16x8 a0 = *(const h16x8*)pl;
        h16x8 a1 = *(const h16x8*)(pl + 8);
        h16x8 c0 = *(const h16x8*)pr;
        h16x8 c1 = *(const h16x8*)(pr + 8);

        float s = 0.f;
        #pragma unroll
        for (int j = 0; j < 8; ++j) {
            float v = (float)a0[j] + (float)c0[j];
            v = fmaxf(v, 0.f);
            s = fmaf(v, w2v[j], s);
        }
        #pragma unroll
        for (int j = 0; j < 8; ++j) {
            float v = (float)a1[j] + (float)c1[j];
            v = fmaxf(v, 0.f);
            s = fmaf(v, w2v[8 + j], s);
        }
        // reduce over the 8 lanes of this edge (xor stays within the group)
        s += __shfl_xor(s, 1);
        s += __shfl_xor(s, 2);
        s += __shfl_xor(s, 4);

        if (sub == 0) {
            s += b2[0];
            s = fmaxf(s, 0.f);
            out[e] = 1.0f / (1.0f + expf(-s));
        }
    }
}

// ---------------- R2 fallback (fused edge-wise GEMM, fp32 inputs) ----------------
__global__ __launch_bounds__(256) void decoder_fallback_kernel(
    const float* __restrict__ x, const int* __restrict__ ei,
    const float* __restrict__ W1, const float* __restrict__ b1,
    const float* __restrict__ W2, const float* __restrict__ b2,
    float* __restrict__ out, int E)
{
    __shared__ int   nid[2][BM];
    __shared__ short At[BM * LDT];
    __shared__ short Bt[D * LDT];
    __shared__ float rowsum[BM][2];

    const int tid = threadIdx.x;
    const int e0  = blockIdx.x * BM;
    if (tid < BM) { int e = e0 + tid; nid[0][tid] = (e < E) ? ei[e] : 0; }
    else { int e = e0 + (tid - BM); nid[1][tid - BM] = (e < E) ? ei[E + e] : 0; }

    const int wid = tid >> 6, lane = tid & 63;
    const int wm = wid >> 1, wn = wid & 1;
    const int quad = lane >> 4, l15 = lane & 15;
    const int srow = tid >> 4, scol = (tid & 15) * 4;
    f32x4 acc[4][4] = {};
    __syncthreads();

    for (int t = 0; t < 4; ++t) {
        const int* ids = nid[t >> 1];
        const int kx = (t & 1) * BK, kw = t * BK;
        #pragma unroll
        for (int p = 0; p < 8; ++p) {
            int row = srow + p * 16;
            float4 v = *(const float4*)&x[(size_t)ids[row] * D + kx + scol];
            s16x4 bv = { f2bf(v.x), f2bf(v.y), f2bf(v.z), f2bf(v.w) };
            *(s16x4*)&At[row * LDT + scol] = bv;
        }
        #pragma unroll
        for (int p = 0; p < 8; ++p) {
            int n = srow + p * 16;
            float4 v = *(const float4*)&W1[n * 256 + kw + scol];
            s16x4 bv = { f2bf(v.x), f2bf(v.y), f2bf(v.z), f2bf(v.w) };
            *(s16x4*)&Bt[n * LDT + scol] = bv;
        }
        __syncthreads();
        #pragma unroll
        for (int c = 0; c < 2; ++c) {
            const int kc = c * 32;
            s16x8 af[4], bfr[4];
            #pragma unroll
            for (int i = 0; i < 4; ++i)
                af[i] = *(const s16x8*)&At[(wm*64 + i*16 + l15) * LDT + kc + quad*8];
            #pragma unroll
            for (int j = 0; j < 4; ++j)
                bfr[j] = *(const s16x8*)&Bt[(wn*64 + j*16 + l15) * LDT + kc + quad*8];
            #pragma unroll
            for (int i = 0; i < 4; ++i)
                #pragma unroll
                for (int j = 0; j < 4; ++j)
                    acc[i][j] = __builtin_amdgcn_mfma_f32_16x16x32_bf16(
                        af[i], bfr[j], acc[i][j], 0, 0, 0);
        }
        __syncthreads();
    }
    float b1v[4], w2v[4];
    #pragma unroll
    for (int j = 0; j < 4; ++j) {
        int col = wn*64 + j*16 + l15;
        b1v[j] = b1[col]; w2v[j] = W2[col];
    }
    float psum[16];
    #pragma unroll
    for (int t = 0; t < 16; ++t) psum[t] = 0.f;
    #pragma unroll
    for (int i = 0; i < 4; ++i)
        #pragma unroll
        for (int j = 0; j < 4; ++j)
            #pragma unroll
            for (int r = 0; r < 4; ++r) {
                float c = fmaxf(acc[i][j][r] + b1v[j], 0.f);
                psum[i*4 + r] += c * w2v[j];
            }
    #pragma unroll
    for (int off = 1; off < 16; off <<= 1)
        #pragma unroll
        for (int t = 0; t < 16; ++t)
            psum[t] += __shfl_xor(psum[t], off);
    if (l15 == 0) {
        #pragma unroll
        for (int i = 0; i < 4; ++i)
            #pragma unroll
            for (int r = 0; r < 4; ++r)
                rowsum[wm*64 + i*16 + quad*4 + r][wn] = psum[i*4 + r];
    }
    __syncthreads();
    if (tid < BM) {
        int e = e0 + tid;
        if (e < E) {
            float s = rowsum[tid][0] + rowsum[tid][1] + b2[0];
            s = fmaxf(s, 0.f);
            out[e] = 1.0f / (1.0f + expf(-s));
        }
    }
}

extern "C" void kernel_launch(void* const* d_in, const int* in_sizes, int n_in,
                              void* d_out, int out_size, void* d_ws, size_t ws_size,
                              hipStream_t stream) {
    const float* x  = (const float*)d_in[0];
    const int*   ei = (const int*)d_in[1];
    const float* W1 = (const float*)d_in[2];
    const float* b1 = (const float*)d_in[3];
    const float* W2 = (const float*)d_in[4];
    const float* b2 = (const float*)d_in[5];
    float* out = (float*)d_out;

    int E = in_sizes[1] / 2;
    int N = in_sizes[0] / D;

    size_t need = (size_t)N * 256 * sizeof(_Float16);   // 51.2 MB for N=100k
    if (ws_size >= need) {
        _Float16* Y = (_Float16*)d_ws;
        dim3 gridA((N + BM - 1) / BM, 2);
        precompute_kernel<<<gridA, 256, 0, stream>>>(x, W1, b1, Y, N);
        int gridB = (E + 31) / 32;
        edge_kernel<<<gridB, 256, 0, stream>>>(Y, ei, W2, b2, out, E);
    } else {
        int nblocks = (E + BM - 1) / BM;
        decoder_fallback_kernel<<<nblocks, 256, 0, stream>>>(
            x, ei, W1, b1, W2, b2, out, E);
    }
}

// Round 4
// 168.983 us; speedup vs baseline: 1.0798x; 1.0798x over previous
//
#include <hip/hip_runtime.h>
#include <hip/hip_bf16.h>
#include <hip/hip_fp16.h>
#include <math.h>

// Decoder: out[e] = sigmoid(relu( W2 . relu( W1 * [x[src]; x[dst]] + b1 ) + b2 ))
// R3 factorization: W1*[xs;xd] = W1_left*xs + W1_right*xd
//   Phase A (per node): Y[n][0:128] = W1_left*x[n] + b1 ; Y[n][128:256] = W1_right*x[n]
//   Phase B (per edge): out = sigmoid(relu(W2 . relu(Yl[src]+Yr[dst]) + b2))
// R4: Phase A rebuilt: 64 nodes x 256 cols per block, K=128 single pass,
//     W1 frags direct from global (L2), epilogue transposed through LDS for
//     coalesced 16B stores (fixes 1.7x write amplification seen in R3 rocprof).

typedef short    s16x4 __attribute__((ext_vector_type(4)));
typedef short    s16x8 __attribute__((ext_vector_type(8)));
typedef float    f32x4 __attribute__((ext_vector_type(4)));
typedef _Float16 h16x8 __attribute__((ext_vector_type(8)));

#define D    128
#define AM   64        // nodes per block (phase A)
#define ALD  136       // 128 + 8 shorts pad (At)
#define CLD  260       // 256 + 4 shorts pad (Cout) ; 2*CLD%32==8 -> quads on disjoint banks

static __device__ inline short f2bf(float f) {
    unsigned u = __builtin_bit_cast(unsigned, f);
    unsigned r = (u + 0x7FFFu + ((u >> 16) & 1u)) >> 16;
    return (short)r;
}

// ---------------- Phase A ----------------
__global__ __launch_bounds__(256) void precompute_kernel(
    const float* __restrict__ x,    // [N,128]
    const float* __restrict__ W1,   // [128,256] row-major
    const float* __restrict__ b1,   // [128]
    _Float16*    __restrict__ Y,    // [N,256]
    int N)
{
    __shared__ __align__(16) char smem[AM * CLD * 2];   // 33280 B
    short*    At   = (short*)smem;                       // [AM][ALD] (17408 B, aliased)
    _Float16* Cout = (_Float16*)smem;                    // [AM][CLD]

    const int tid  = threadIdx.x;
    const int m0   = blockIdx.x * AM;
    const int wid  = tid >> 6;
    const int lane = tid & 63;
    const int quad = lane >> 4, l15 = lane & 15;

    // ---- stage x tile: 64 rows x 128 k, fp32 -> bf16 (issue global loads first)
    float4 xv[8];
    #pragma unroll
    for (int p = 0; p < 8; ++p) {
        int row = p * 8 + (tid >> 5);
        int m   = m0 + row; if (m >= N) m = N - 1;
        int col = (tid & 31) * 4;
        xv[p] = *(const float4*)&x[(size_t)m * D + col];
    }

    // ---- B fragments straight from global W1 (L2-resident), fp32 -> bf16
    // B[n=o][k] = W1[o&127][(o>>7)*128 + k], o = wid*64 + j*16 + l15
    s16x8 bf[4][4];   // [k-chunk][col-tile]
    #pragma unroll
    for (int j = 0; j < 4; ++j) {
        int o = wid * 64 + j * 16 + l15;
        const float* wp = W1 + (size_t)(o & 127) * 256 + ((o >> 7) * 128) + quad * 8;
        #pragma unroll
        for (int c = 0; c < 4; ++c) {
            float4 u0 = *(const float4*)(wp + c * 32);
            float4 u1 = *(const float4*)(wp + c * 32 + 4);
            bf[c][j] = (s16x8){ f2bf(u0.x), f2bf(u0.y), f2bf(u0.z), f2bf(u0.w),
                                f2bf(u1.x), f2bf(u1.y), f2bf(u1.z), f2bf(u1.w) };
        }
    }

    #pragma unroll
    for (int p = 0; p < 8; ++p) {
        int row = p * 8 + (tid >> 5);
        int col = (tid & 31) * 4;
        s16x4 bv = { f2bf(xv[p].x), f2bf(xv[p].y), f2bf(xv[p].z), f2bf(xv[p].w) };
        *(s16x4*)&At[row * ALD + col] = bv;
    }
    __syncthreads();

    // ---- MFMA: 4 k-chunks x (4 row-tiles x 4 col-tiles)
    f32x4 acc[4][4] = {};   // [row-tile][col-tile]
    #pragma unroll
    for (int c = 0; c < 4; ++c) {
        const int kc = c * 32;
        s16x8 af[4];
        #pragma unroll
        for (int i = 0; i < 4; ++i)
            af[i] = *(const s16x8*)&At[(i * 16 + l15) * ALD + kc + quad * 8];
        #pragma unroll
        for (int i = 0; i < 4; ++i)
            #pragma unroll
            for (int j = 0; j < 4; ++j)
                acc[i][j] = __builtin_amdgcn_mfma_f32_16x16x32_bf16(
                    af[i], bf[c][j], acc[i][j], 0, 0, 0);
    }
    __syncthreads();   // all waves done reading At before Cout overwrites it

    // ---- epilogue: bias, fp16, transpose through LDS
    // C/D layout: col = lane&15, row = quad*4 + reg
    #pragma unroll
    for (int j = 0; j < 4; ++j) {
        int o = wid * 64 + j * 16 + l15;
        float bb = (o < 128) ? b1[o] : 0.f;
        #pragma unroll
        for (int i = 0; i < 4; ++i) {
            int rl = i * 16 + quad * 4;
            #pragma unroll
            for (int r = 0; r < 4; ++r)
                Cout[(rl + r) * CLD + o] = (_Float16)(acc[i][j][r] + bb);
        }
    }
    __syncthreads();

    // ---- coalesced store: 4 threads per row, 64 cols each, 16B chunks
    {
        int row = tid >> 2;
        int m   = m0 + row;
        if (m < N) {
            int c0 = (tid & 3) * 64;
            #pragma unroll
            for (int p = 0; p < 8; ++p) {
                h16x8 v = *(const h16x8*)&Cout[row * CLD + c0 + p * 8];
                *(h16x8*)&Y[(size_t)m * 256 + c0 + p * 8] = v;
            }
        }
    }
}

// ---------------- Phase B: per-edge streaming gather + dot(128) + sigmoid
__global__ __launch_bounds__(256) void edge_kernel(
    const _Float16* __restrict__ Y,   // [N,256]
    const int*      __restrict__ ei,  // [2,E]
    const float*    __restrict__ W2,  // [128]
    const float*    __restrict__ b2,  // [1]
    float*          __restrict__ out, // [E]
    int E)
{
    const int tid = threadIdx.x;
    const int sub = tid & 7;                    // 8 lanes per edge
    const int e   = blockIdx.x * 32 + (tid >> 3);

    float w2v[16];
    *(float4*)&w2v[0]  = *(const float4*)&W2[sub*16 + 0];
    *(float4*)&w2v[4]  = *(const float4*)&W2[sub*16 + 4];
    *(float4*)&w2v[8]  = *(const float4*)&W2[sub*16 + 8];
    *(float4*)&w2v[12] = *(const float4*)&W2[sub*16 + 12];

    if (e < E) {
        int src = ei[e];
        int dst = ei[E + e];
        const _Float16* pl = Y + (size_t)src * 256 + sub * 16;
        const _Float16* pr = Y + (size_t)dst * 256 + 128 + sub * 16;
        h16x8 a0 = *(const h16x8*)pl;
        h16x8 a1 = *(const h16x8*)(pl + 8);
        h16x8 c0 = *(const h16x8*)pr;
        h16x8 c1 = *(const h16x8*)(pr + 8);

        float s = 0.f;
        #pragma unroll
        for (int j = 0; j < 8; ++j) {
            float v = (float)a0[j] + (float)c0[j];
            v = fmaxf(v, 0.f);
            s = fmaf(v, w2v[j], s);
        }
        #pragma unroll
        for (int j = 0; j < 8; ++j) {
            float v = (float)a1[j] + (float)c1[j];
            v = fmaxf(v, 0.f);
            s = fmaf(v, w2v[8 + j], s);
        }
        s += __shfl_xor(s, 1);
        s += __shfl_xor(s, 2);
        s += __shfl_xor(s, 4);

        if (sub == 0) {
            s += b2[0];
            s = fmaxf(s, 0.f);
            out[e] = 1.0f / (1.0f + expf(-s));
        }
    }
}

// ---------------- fallback (fused edge-wise GEMM, fp32 inputs) ----------------
#define BM   128
#define BK   64
#define LDT  72

__global__ __launch_bounds__(256) void decoder_fallback_kernel(
    const float* __restrict__ x, const int* __restrict__ ei,
    const float* __restrict__ W1, const float* __restrict__ b1,
    const float* __restrict__ W2, const float* __restrict__ b2,
    float* __restrict__ out, int E)
{
    __shared__ int   nid[2][BM];
    __shared__ short At[BM * LDT];
    __shared__ short Bt[D * LDT];
    __shared__ float rowsum[BM][2];

    const int tid = threadIdx.x;
    const int e0  = blockIdx.x * BM;
    if (tid < BM) { int e = e0 + tid; nid[0][tid] = (e < E) ? ei[e] : 0; }
    else { int e = e0 + (tid - BM); nid[1][tid - BM] = (e < E) ? ei[E + e] : 0; }

    const int wid = tid >> 6, lane = tid & 63;
    const int wm = wid >> 1, wn = wid & 1;
    const int quad = lane >> 4, l15 = lane & 15;
    const int srow = tid >> 4, scol = (tid & 15) * 4;
    f32x4 acc[4][4] = {};
    __syncthreads();

    for (int t = 0; t < 4; ++t) {
        const int* ids = nid[t >> 1];
        const int kx = (t & 1) * BK, kw = t * BK;
        #pragma unroll
        for (int p = 0; p < 8; ++p) {
            int row = srow + p * 16;
            float4 v = *(const float4*)&x[(size_t)ids[row] * D + kx + scol];
            s16x4 bv = { f2bf(v.x), f2bf(v.y), f2bf(v.z), f2bf(v.w) };
            *(s16x4*)&At[row * LDT + scol] = bv;
        }
        #pragma unroll
        for (int p = 0; p < 8; ++p) {
            int n = srow + p * 16;
            float4 v = *(const float4*)&W1[n * 256 + kw + scol];
            s16x4 bv = { f2bf(v.x), f2bf(v.y), f2bf(v.z), f2bf(v.w) };
            *(s16x4*)&Bt[n * LDT + scol] = bv;
        }
        __syncthreads();
        #pragma unroll
        for (int c = 0; c < 2; ++c) {
            const int kc = c * 32;
            s16x8 af[4], bfr[4];
            #pragma unroll
            for (int i = 0; i < 4; ++i)
                af[i] = *(const s16x8*)&At[(wm*64 + i*16 + l15) * LDT + kc + quad*8];
            #pragma unroll
            for (int j = 0; j < 4; ++j)
                bfr[j] = *(const s16x8*)&Bt[(wn*64 + j*16 + l15) * LDT + kc + quad*8];
            #pragma unroll
            for (int i = 0; i < 4; ++i)
                #pragma unroll
                for (int j = 0; j < 4; ++j)
                    acc[i][j] = __builtin_amdgcn_mfma_f32_16x16x32_bf16(
                        af[i], bfr[j], acc[i][j], 0, 0, 0);
        }
        __syncthreads();
    }
    float b1v[4], w2v[4];
    #pragma unroll
    for (int j = 0; j < 4; ++j) {
        int col = wn*64 + j*16 + l15;
        b1v[j] = b1[col]; w2v[j] = W2[col];
    }
    float psum[16];
    #pragma unroll
    for (int t = 0; t < 16; ++t) psum[t] = 0.f;
    #pragma unroll
    for (int i = 0; i < 4; ++i)
        #pragma unroll
        for (int j = 0; j < 4; ++j)
            #pragma unroll
            for (int r = 0; r < 4; ++r) {
                float c = fmaxf(acc[i][j][r] + b1v[j], 0.f);
                psum[i*4 + r] += c * w2v[j];
            }
    #pragma unroll
    for (int off = 1; off < 16; off <<= 1)
        #pragma unroll
        for (int t = 0; t < 16; ++t)
            psum[t] += __shfl_xor(psum[t], off);
    if (l15 == 0) {
        #pragma unroll
        for (int i = 0; i < 4; ++i)
            #pragma unroll
            for (int r = 0; r < 4; ++r)
                rowsum[wm*64 + i*16 + quad*4 + r][wn] = psum[i*4 + r];
    }
    __syncthreads();
    if (tid < BM) {
        int e = e0 + tid;
        if (e < E) {
            float s = rowsum[tid][0] + rowsum[tid][1] + b2[0];
            s = fmaxf(s, 0.f);
            out[e] = 1.0f / (1.0f + expf(-s));
        }
    }
}

extern "C" void kernel_launch(void* const* d_in, const int* in_sizes, int n_in,
                              void* d_out, int out_size, void* d_ws, size_t ws_size,
                              hipStream_t stream) {
    const float* x  = (const float*)d_in[0];
    const int*   ei = (const int*)d_in[1];
    const float* W1 = (const float*)d_in[2];
    const float* b1 = (const float*)d_in[3];
    const float* W2 = (const float*)d_in[4];
    const float* b2 = (const float*)d_in[5];
    float* out = (float*)d_out;

    int E = in_sizes[1] / 2;
    int N = in_sizes[0] / D;

    size_t need = (size_t)N * 256 * sizeof(_Float16);   // 51.2 MB for N=100k
    if (ws_size >= need) {
        _Float16* Y = (_Float16*)d_ws;
        int gridA = (N + AM - 1) / AM;
        precompute_kernel<<<gridA, 256, 0, stream>>>(x, W1, b1, Y, N);
        int gridB = (E + 31) / 32;
        edge_kernel<<<gridB, 256, 0, stream>>>(Y, ei, W2, b2, out, E);
    } else {
        int nblocks = (E + BM - 1) / BM;
        decoder_fallback_kernel<<<nblocks, 256, 0, stream>>>(
            x, ei, W1, b1, W2, b2, out, E);
    }
}

// Round 5
// 164.516 us; speedup vs baseline: 1.1091x; 1.0271x over previous
//
#include <hip/hip_runtime.h>
#include <hip/hip_bf16.h>
#include <hip/hip_fp16.h>
#include <math.h>

// Decoder: out[e] = sigmoid(relu( W2 . relu( W1 * [x[src]; x[dst]] + b1 ) + b2 ))
// Factorized: Y[n][0:128] = W1_left*x[n] + b1 ; Y[n][128:256] = W1_right*x[n]
//             out[e] = sigmoid(relu( W2 . relu(Yl[src]+Yr[dst]) + b2 ))
// R5: W1 pre-packed to bf16 in MFMA-fragment order (W1F). R4's precompute was
//     bound by VMEM request serialization: W1 frag loads had 1KB lane stride
//     -> 64 cache lines per instruction x 32 instrs/thread. W1F loads are
//     16B/lane fully coalesced (8 lines/instr, 16 instrs).

typedef short    s16x4 __attribute__((ext_vector_type(4)));
typedef short    s16x8 __attribute__((ext_vector_type(8)));
typedef float    f32x4 __attribute__((ext_vector_type(4)));
typedef _Float16 h16x8 __attribute__((ext_vector_type(8)));

#define D    128
#define AM   64        // nodes per block (phase A)
#define ALD  136       // 128 + 8 shorts pad (At)
#define CLD  260       // 256 + 4 shorts pad (Cout)

static __device__ inline short f2bf(float f) {
    unsigned u = __builtin_bit_cast(unsigned, f);
    unsigned r = (u + 0x7FFFu + ((u >> 16) & 1u)) >> 16;
    return (short)r;
}

// ---------------- pack W1 -> bf16 fragment order ----------------
// W1F[g*8 .. g*8+8) , g = wid*1024 + j*256 + c*64 + lane
//   o  = wid*64 + j*16 + (lane&15)          (Y output col)
//   kb = c*32 + (lane>>4)*8                 (k offset)
//   B[o][k] = W1[o&127][(o>>7)*128 + k]
__global__ __launch_bounds__(256) void pack_w1_kernel(
    const float* __restrict__ W1, short* __restrict__ W1F)
{
    int g    = blockIdx.x * 256 + threadIdx.x;   // 0..4095
    int lane = g & 63;
    int c    = (g >> 6) & 3;
    int j    = (g >> 8) & 3;
    int wid  = g >> 10;
    int o    = wid * 64 + j * 16 + (lane & 15);
    int kb   = c * 32 + (lane >> 4) * 8;
    const float* wp = W1 + (size_t)(o & 127) * 256 + (o >> 7) * 128 + kb;
    float4 u0 = *(const float4*)wp;
    float4 u1 = *(const float4*)(wp + 4);
    s16x8 v = { f2bf(u0.x), f2bf(u0.y), f2bf(u0.z), f2bf(u0.w),
                f2bf(u1.x), f2bf(u1.y), f2bf(u1.z), f2bf(u1.w) };
    *(s16x8*)&W1F[(size_t)g * 8] = v;
}

// ---------------- Phase A ----------------
__global__ __launch_bounds__(256) void precompute_kernel(
    const float* __restrict__ x,    // [N,128]
    const short* __restrict__ W1F,  // packed bf16 fragments (32768)
    const float* __restrict__ b1,   // [128]
    _Float16*    __restrict__ Y,    // [N,256]
    int N)
{
    __shared__ __align__(16) char smem[AM * CLD * 2];   // 33280 B
    short*    At   = (short*)smem;                       // [AM][ALD] (aliased)
    _Float16* Cout = (_Float16*)smem;                    // [AM][CLD]

    const int tid  = threadIdx.x;
    const int m0   = blockIdx.x * AM;
    const int wid  = tid >> 6;
    const int lane = tid & 63;
    const int quad = lane >> 4, l15 = lane & 15;

    // ---- issue x tile loads first (HBM, longest latency)
    float4 xv[8];
    #pragma unroll
    for (int p = 0; p < 8; ++p) {
        int row = p * 8 + (tid >> 5);
        int m   = m0 + row; if (m >= N) m = N - 1;
        int col = (tid & 31) * 4;
        xv[p] = *(const float4*)&x[(size_t)m * D + col];
    }

    // ---- B fragments: coalesced 16B/lane loads from packed W1F (L2-hot)
    s16x8 bf[4][4];   // [k-chunk][col-tile]
    #pragma unroll
    for (int j = 0; j < 4; ++j)
        #pragma unroll
        for (int c = 0; c < 4; ++c)
            bf[c][j] = *(const s16x8*)&W1F[(size_t)(((wid * 4 + j) * 4 + c) * 64 + lane) * 8];

    // ---- convert + stage x tile
    #pragma unroll
    for (int p = 0; p < 8; ++p) {
        int row = p * 8 + (tid >> 5);
        int col = (tid & 31) * 4;
        s16x4 bv = { f2bf(xv[p].x), f2bf(xv[p].y), f2bf(xv[p].z), f2bf(xv[p].w) };
        *(s16x4*)&At[row * ALD + col] = bv;
    }
    __syncthreads();

    // ---- MFMA: 4 k-chunks x (4 row-tiles x 4 col-tiles)
    f32x4 acc[4][4] = {};   // [row-tile][col-tile]
    #pragma unroll
    for (int c = 0; c < 4; ++c) {
        const int kc = c * 32;
        s16x8 af[4];
        #pragma unroll
        for (int i = 0; i < 4; ++i)
            af[i] = *(const s16x8*)&At[(i * 16 + l15) * ALD + kc + quad * 8];
        #pragma unroll
        for (int i = 0; i < 4; ++i)
            #pragma unroll
            for (int j = 0; j < 4; ++j)
                acc[i][j] = __builtin_amdgcn_mfma_f32_16x16x32_bf16(
                    af[i], bf[c][j], acc[i][j], 0, 0, 0);
    }
    __syncthreads();   // all waves done reading At before Cout overwrites it

    // ---- epilogue: bias, fp16, transpose through LDS
    // C/D layout: col = lane&15, row = quad*4 + reg
    #pragma unroll
    for (int j = 0; j < 4; ++j) {
        int o = wid * 64 + j * 16 + l15;
        float bb = (o < 128) ? b1[o] : 0.f;
        #pragma unroll
        for (int i = 0; i < 4; ++i) {
            int rl = i * 16 + quad * 4;
            #pragma unroll
            for (int r = 0; r < 4; ++r)
                Cout[(rl + r) * CLD + o] = (_Float16)(acc[i][j][r] + bb);
        }
    }
    __syncthreads();

    // ---- coalesced store: 4 threads per row, 64 cols each, 16B chunks
    {
        int row = tid >> 2;
        int m   = m0 + row;
        if (m < N) {
            int c0 = (tid & 3) * 64;
            #pragma unroll
            for (int p = 0; p < 8; ++p) {
                h16x8 v = *(const h16x8*)&Cout[row * CLD + c0 + p * 8];
                *(h16x8*)&Y[(size_t)m * 256 + c0 + p * 8] = v;
            }
        }
    }
}

// ---------------- Phase B: per-edge streaming gather + dot(128) + sigmoid
__global__ __launch_bounds__(256) void edge_kernel(
    const _Float16* __restrict__ Y,   // [N,256]
    const int*      __restrict__ ei,  // [2,E]
    const float*    __restrict__ W2,  // [128]
    const float*    __restrict__ b2,  // [1]
    float*          __restrict__ out, // [E]
    int E)
{
    const int tid = threadIdx.x;
    const int sub = tid & 7;                    // 8 lanes per edge
    const int e   = blockIdx.x * 32 + (tid >> 3);

    float w2v[16];
    *(float4*)&w2v[0]  = *(const float4*)&W2[sub*16 + 0];
    *(float4*)&w2v[4]  = *(const float4*)&W2[sub*16 + 4];
    *(float4*)&w2v[8]  = *(const float4*)&W2[sub*16 + 8];
    *(float4*)&w2v[12] = *(const float4*)&W2[sub*16 + 12];

    if (e < E) {
        int src = ei[e];
        int dst = ei[E + e];
        const _Float16* pl = Y + (size_t)src * 256 + sub * 16;
        const _Float16* pr = Y + (size_t)dst * 256 + 128 + sub * 16;
        h16x8 a0 = *(const h16x8*)pl;
        h16x8 a1 = *(const h16x8*)(pl + 8);
        h16x8 c0 = *(const h16x8*)pr;
        h16x8 c1 = *(const h16x8*)(pr + 8);

        float s = 0.f;
        #pragma unroll
        for (int j = 0; j < 8; ++j) {
            float v = (float)a0[j] + (float)c0[j];
            v = fmaxf(v, 0.f);
            s = fmaf(v, w2v[j], s);
        }
        #pragma unroll
        for (int j = 0; j < 8; ++j) {
            float v = (float)a1[j] + (float)c1[j];
            v = fmaxf(v, 0.f);
            s = fmaf(v, w2v[8 + j], s);
        }
        s += __shfl_xor(s, 1);
        s += __shfl_xor(s, 2);
        s += __shfl_xor(s, 4);

        if (sub == 0) {
            s += b2[0];
            s = fmaxf(s, 0.f);
            out[e] = 1.0f / (1.0f + expf(-s));
        }
    }
}

// ---------------- fallback (fused edge-wise GEMM, fp32 inputs) ----------------
#define BM   128
#define BK   64
#define LDT  72

__global__ __launch_bounds__(256) void decoder_fallback_kernel(
    const float* __restrict__ x, const int* __restrict__ ei,
    const float* __restrict__ W1, const float* __restrict__ b1,
    const float* __restrict__ W2, const float* __restrict__ b2,
    float* __restrict__ out, int E)
{
    __shared__ int   nid[2][BM];
    __shared__ short At[BM * LDT];
    __shared__ short Bt[D * LDT];
    __shared__ float rowsum[BM][2];

    const int tid = threadIdx.x;
    const int e0  = blockIdx.x * BM;
    if (tid < BM) { int e = e0 + tid; nid[0][tid] = (e < E) ? ei[e] : 0; }
    else { int e = e0 + (tid - BM); nid[1][tid - BM] = (e < E) ? ei[E + e] : 0; }

    const int wid = tid >> 6, lane = tid & 63;
    const int wm = wid >> 1, wn = wid & 1;
    const int quad = lane >> 4, l15 = lane & 15;
    const int srow = tid >> 4, scol = (tid & 15) * 4;
    f32x4 acc[4][4] = {};
    __syncthreads();

    for (int t = 0; t < 4; ++t) {
        const int* ids = nid[t >> 1];
        const int kx = (t & 1) * BK, kw = t * BK;
        #pragma unroll
        for (int p = 0; p < 8; ++p) {
            int row = srow + p * 16;
            float4 v = *(const float4*)&x[(size_t)ids[row] * D + kx + scol];
            s16x4 bv = { f2bf(v.x), f2bf(v.y), f2bf(v.z), f2bf(v.w) };
            *(s16x4*)&At[row * LDT + scol] = bv;
        }
        #pragma unroll
        for (int p = 0; p < 8; ++p) {
            int n = srow + p * 16;
            float4 v = *(const float4*)&W1[n * 256 + kw + scol];
            s16x4 bv = { f2bf(v.x), f2bf(v.y), f2bf(v.z), f2bf(v.w) };
            *(s16x4*)&Bt[n * LDT + scol] = bv;
        }
        __syncthreads();
        #pragma unroll
        for (int c = 0; c < 2; ++c) {
            const int kc = c * 32;
            s16x8 af[4], bfr[4];
            #pragma unroll
            for (int i = 0; i < 4; ++i)
                af[i] = *(const s16x8*)&At[(wm*64 + i*16 + l15) * LDT + kc + quad*8];
            #pragma unroll
            for (int j = 0; j < 4; ++j)
                bfr[j] = *(const s16x8*)&Bt[(wn*64 + j*16 + l15) * LDT + kc + quad*8];
            #pragma unroll
            for (int i = 0; i < 4; ++i)
                #pragma unroll
                for (int j = 0; j < 4; ++j)
                    acc[i][j] = __builtin_amdgcn_mfma_f32_16x16x32_bf16(
                        af[i], bfr[j], acc[i][j], 0, 0, 0);
        }
        __syncthreads();
    }
    float b1v[4], w2v[4];
    #pragma unroll
    for (int j = 0; j < 4; ++j) {
        int col = wn*64 + j*16 + l15;
        b1v[j] = b1[col]; w2v[j] = W2[col];
    }
    float psum[16];
    #pragma unroll
    for (int t = 0; t < 16; ++t) psum[t] = 0.f;
    #pragma unroll
    for (int i = 0; i < 4; ++i)
        #pragma unroll
        for (int j = 0; j < 4; ++j)
            #pragma unroll
            for (int r = 0; r < 4; ++r) {
                float c = fmaxf(acc[i][j][r] + b1v[j], 0.f);
                psum[i*4 + r] += c * w2v[j];
            }
    #pragma unroll
    for (int off = 1; off < 16; off <<= 1)
        #pragma unroll
        for (int t = 0; t < 16; ++t)
            psum[t] += __shfl_xor(psum[t], off);
    if (l15 == 0) {
        #pragma unroll
        for (int i = 0; i < 4; ++i)
            #pragma unroll
            for (int r = 0; r < 4; ++r)
                rowsum[wm*64 + i*16 + quad*4 + r][wn] = psum[i*4 + r];
    }
    __syncthreads();
    if (tid < BM) {
        int e = e0 + tid;
        if (e < E) {
            float s = rowsum[tid][0] + rowsum[tid][1] + b2[0];
            s = fmaxf(s, 0.f);
            out[e] = 1.0f / (1.0f + expf(-s));
        }
    }
}

extern "C" void kernel_launch(void* const* d_in, const int* in_sizes, int n_in,
                              void* d_out, int out_size, void* d_ws, size_t ws_size,
                              hipStream_t stream) {
    const float* x  = (const float*)d_in[0];
    const int*   ei = (const int*)d_in[1];
    const float* W1 = (const float*)d_in[2];
    const float* b1 = (const float*)d_in[3];
    const float* W2 = (const float*)d_in[4];
    const float* b2 = (const float*)d_in[5];
    float* out = (float*)d_out;

    int E = in_sizes[1] / 2;
    int N = in_sizes[0] / D;

    size_t y_bytes = (size_t)N * 256 * sizeof(_Float16);       // 51.2 MB
    size_t need    = y_bytes + 32768 * sizeof(short);          // + 64 KB W1F
    if (ws_size >= need) {
        _Float16* Y   = (_Float16*)d_ws;
        short*    W1F = (short*)((char*)d_ws + y_bytes);
        pack_w1_kernel<<<16, 256, 0, stream>>>(W1, W1F);
        int gridA = (N + AM - 1) / AM;
        precompute_kernel<<<gridA, 256, 0, stream>>>(x, W1F, b1, Y, N);
        int gridB = (E + 31) / 32;
        edge_kernel<<<gridB, 256, 0, stream>>>(Y, ei, W2, b2, out, E);
    } else {
        int nblocks = (E + BM - 1) / BM;
        decoder_fallback_kernel<<<nblocks, 256, 0, stream>>>(
            x, ei, W1, b1, W2, b2, out, E);
    }
}